// Round 5
// baseline (169.917 us; speedup 1.0000x reference)
//
#include <hip/hip_runtime.h>
#include <hip/hip_bf16.h>
#include <math.h>

// Problem constants
#define NP 121
#define DD 512
#define INV_SQRT_D 0.04419417382415922f

// Workspace layout (float offsets)
#define O_X     0         // 512    relu(b_first)
#define O_KVX   512       // 2048   W_kvx@x + b_kvx
#define O_QV    2560      // 1024   W_q@x + b_q
#define O_POS   3584      // 121*18 positional features
#define O_W     5762      // 2*25   attention feature weights per head
#define O_VC    5812      // 1024   v-const
#define O_PC    6836      // 2*121  positional part of attn logits
#define O_CFIN  7078      // 512
#define O_C2    7590      // 512
#define O_T1    8102      // 2*512*25
#define O_T2    33702     // 2*512*25
#define O_QC    59302     // 2*512
#define O_T3    60326     // 2*2*512*25
#define O_P     111526    // 2*19*51  folded policy matrices
// total 113464 floats (~454 KB)

// ---------------- S1: positional features + x = relu(b_first) ----------------
__global__ void s1_pos_x(const float* __restrict__ b_first, float* __restrict__ ws) {
    int t = threadIdx.x;
    const float TWO_PI = 6.283185307179586f;
    for (int p = t; p < NP; p += blockDim.x) {
        int i = p / 11, j = p % 11;
        float r = (i - 5) * 0.2f, c = (j - 5) * 0.2f, z = 0.5f * (r + c);
        float xs[3] = {r, c, z};
        float pp[3] = {1.f, 2.f, 4.f};
        for (int a = 0; a < 3; a++)
            for (int q = 0; q < 3; q++) {
                float ang = TWO_PI * xs[q] / pp[a];
                ws[O_POS + p * 18 + a * 3 + q]     = cosf(ang);
                ws[O_POS + p * 18 + 9 + a * 3 + q] = sinf(ang);
            }
    }
    for (int d = t; d < DD; d += blockDim.x) ws[O_X + d] = fmaxf(b_first[d], 0.f);
}

// ---------------- S2: kvx = W_kvx@x + b_kvx ; qv = W_q@x + b_q ----------------
__global__ void s2_kvx_qv(const float* __restrict__ W_kvx, const float* __restrict__ b_kvx,
                          const float* __restrict__ W_q, const float* __restrict__ b_q,
                          float* __restrict__ ws) {
    __shared__ float xs[DD];
    int t = threadIdx.x;
    for (int d = t; d < DD; d += 256) xs[d] = ws[O_X + d];
    __syncthreads();
    int wid = blockIdx.x * 4 + (t >> 6), lane = t & 63;
    const float* row; float bias; int outIdx;
    if (wid < 2048) { row = W_kvx + wid * DD; bias = b_kvx[wid]; outIdx = O_KVX + wid; }
    else { int r = wid - 2048; row = W_q + r * DD; bias = b_q[r]; outIdx = O_QV + r; }
    float acc = 0.f;
    for (int d = lane; d < DD; d += 64) acc += row[d] * xs[d];
    for (int o = 32; o; o >>= 1) acc += __shfl_xor(acc, o, 64);
    if (lane == 0) ws[outIdx] = acc + bias;
}

// ---------------- S3: w_h = q_h^T Wk_h ; vc = kvx_v + b_kvb_v ----------------
__global__ void s3_w_vc(const float* __restrict__ W_kvb, const float* __restrict__ b_kvb,
                        float* __restrict__ ws) {
    int blk = blockIdx.x, t = threadIdx.x;
    if (blk < 13) {
        int wv = blk * 4 + (t >> 6), lane = t & 63;
        if (wv < 50) {
            int h = wv / 25, j = wv % 25;
            float acc = 0.f;
            for (int d = lane; d < 512; d += 64)
                acc += W_kvb[(h * 512 + d) * 25 + j] * ws[O_QV + h * 512 + d];
            for (int o = 32; o; o >>= 1) acc += __shfl_xor(acc, o, 64);
            if (lane == 0) ws[O_W + wv] = acc;
        }
    } else {
        int idx = (blk - 13) * 256 + t;
        if (idx < 1024) ws[O_VC + idx] = ws[O_KVX + 1024 + idx] + b_kvb[1024 + idx];
    }
}

// ---------------- generic 8-row x 25-col GEMM, K=512, LDS staged ----------------
__device__ void gemm8x25(const float* __restrict__ A, int lda,
                         const float* __restrict__ B,    // [512][25] row-major contiguous
                         float* __restrict__ C, int nr) {
    __shared__ float Bl[256 * 25];
    __shared__ float Al[8 * 256];
    int t = threadIdx.x;
    int rl = t / 25, j = t - rl * 25;
    bool act = (t < 200) && (rl < nr);
    float acc = 0.f;
    for (int c = 0; c < 2; c++) {
        __syncthreads();
        for (int idx = t; idx < 6400; idx += 256) Bl[idx] = B[c * 6400 + idx];
        for (int idx = t; idx < 2048; idx += 256) {
            int rr = idx >> 8, dd = idx & 255;
            if (rr < nr) Al[idx] = A[rr * lda + c * 256 + dd];
        }
        __syncthreads();
        if (act) {
            const float* al = &Al[rl * 256];
            for (int dd = 0; dd < 256; dd++) acc += al[dd] * Bl[dd * 25 + j];
        }
    }
    if (act) C[rl * 25 + j] = acc;
}

// ---------------- S4: c_fin ; T1_h = W_fin,h @ Wv_h ; pc ----------------
__global__ void s4(const float* __restrict__ W_fin, const float* __restrict__ b_fin,
                   const float* __restrict__ W_kvb, float* __restrict__ ws) {
    int blk = blockIdx.x, t = threadIdx.x;
    if (blk < 128) {
        int row = blk * 4 + (t >> 6), lane = t & 63;
        float acc = 0.f;
        for (int d = lane; d < 1024; d += 64) acc += W_fin[row * 1024 + d] * ws[O_VC + d];
        for (int o = 32; o; o >>= 1) acc += __shfl_xor(acc, o, 64);
        if (lane == 0) ws[O_CFIN + row] = acc + b_fin[row];
    } else if (blk < 256) {
        int b2 = blk - 128, h = b2 >> 6, chunk = b2 & 63, r0 = chunk * 8;
        gemm8x25(W_fin + r0 * 1024 + h * 512, 1024,
                 W_kvb + (1024 + h * 512) * 25,
                 ws + O_T1 + (h * 512 + r0) * 25, 8);
    } else {
        if (t < 242) {
            int h = t / 121, p = t % 121;
            float acc = 0.f;
            for (int j = 0; j < 18; j++) acc += ws[O_W + h * 25 + 7 + j] * ws[O_POS + p * 18 + j];
            ws[O_PC + h * 121 + p] = acc;
        }
    }
}

// ---------------- S5: c2 ; T2_h = W_sec @ T1_h ----------------
__global__ void s5(const float* __restrict__ W_sec, const float* __restrict__ b_sec,
                   float* __restrict__ ws) {
    int blk = blockIdx.x, t = threadIdx.x;
    if (blk < 128) {
        int row = blk * 4 + (t >> 6), lane = t & 63;
        float acc = 0.f;
        for (int d = lane; d < 512; d += 64) acc += W_sec[row * 512 + d] * ws[O_CFIN + d];
        for (int o = 32; o; o >>= 1) acc += __shfl_xor(acc, o, 64);
        if (lane == 0) ws[O_C2 + row] = acc + b_sec[row];
    } else {
        int b2 = blk - 128, h = b2 >> 6, chunk = b2 & 63, r0 = chunk * 8;
        gemm8x25(W_sec + r0 * 512, 512,
                 ws + O_T1 + (h * 512) * 25,
                 ws + O_T2 + (h * 512 + r0) * 25, 8);
    }
}

// ---------------- S6: qc_i ; T3_{i,h} = W_iq @ T2_h ----------------
__global__ void s6(const float* __restrict__ W0_q, const float* __restrict__ b0_q,
                   const float* __restrict__ W1_q, const float* __restrict__ b1_q,
                   float* __restrict__ ws) {
    int blk = blockIdx.x, t = threadIdx.x;
    if (blk < 256) {
        int row = blk * 4 + (t >> 6), lane = t & 63;
        int i = row >> 9, r = row & 511;
        const float* Wq = i ? W1_q : W0_q;
        const float* bq = i ? b1_q : b0_q;
        float acc = 0.f;
        for (int d = lane; d < 512; d += 64) acc += Wq[r * 512 + d] * ws[O_C2 + d];
        for (int o = 32; o; o >>= 1) acc += __shfl_xor(acc, o, 64);
        if (lane == 0) ws[O_QC + row] = acc + bq[r];
    } else {
        int b2 = blk - 256;
        int i = b2 >> 7, h = (b2 >> 6) & 1, chunk = b2 & 63, r0 = chunk * 8;
        const float* Wq = i ? W1_q : W0_q;
        gemm8x25(Wq + r0 * 512, 512,
                 ws + O_T2 + (h * 512) * 25,
                 ws + O_T3 + ((i * 2 + h) * 512 + r0) * 25, 8);
    }
}

// ---------------- S7: P_i = [b_kp; W_kp^T] @ [qc_i | T3_{i,0} | T3_{i,1}] ----------------
// P layout: ws[O_P + i*969 + r*51 + c], r in 0..18 (0=bias row), c in 0..50
__global__ void s7_fold(const float* __restrict__ W0_kp, const float* __restrict__ b0_kp,
                        const float* __restrict__ W1_kp, const float* __restrict__ b1_kp,
                        float* __restrict__ ws) {
    int gid = blockIdx.x * 4 + (threadIdx.x >> 6);
    int lane = threadIdx.x & 63;
    if (gid >= 1938) return;
    int i = gid / 969, rem = gid % 969, r = rem / 51, c = rem % 51;
    const float* kpW = i ? W1_kp : W0_kp;
    const float* kpb = i ? b1_kp : b0_kp;
    float acc = 0.f;
    for (int d = lane; d < 512; d += 64) {
        float kv = (r == 0) ? kpb[d] : kpW[d * 18 + (r - 1)];
        float gv;
        if (c == 0) gv = ws[O_QC + i * 512 + d];
        else {
            int h = (c - 1) / 25, f = (c - 1) % 25;
            gv = ws[O_T3 + ((i * 2 + h) * 512 + d) * 25 + f];
        }
        acc += kv * gv;
    }
    for (int o = 32; o; o >>= 1) acc += __shfl_xor(acc, o, 64);
    if (lane == 0) ws[O_P + gid] = acc;
}

// ---------------- S8: per-(batch, policy) main; flat 1-D grid of 1024 ----------------
__device__ __forceinline__ float blk_max2(float v, volatile float* tmp) {
    for (int o = 32; o; o >>= 1) v = fmaxf(v, __shfl_xor(v, o, 64));
    __syncthreads();
    if ((threadIdx.x & 63) == 0) tmp[threadIdx.x >> 6] = v;
    __syncthreads();
    return fmaxf(tmp[0], tmp[1]);
}
__device__ __forceinline__ float blk_sum2(float v, volatile float* tmp) {
    for (int o = 32; o; o >>= 1) v += __shfl_xor(v, o, 64);
    __syncthreads();
    if ((threadIdx.x & 63) == 0) tmp[threadIdx.x >> 6] = v;
    __syncthreads();
    return tmp[0] + tmp[1];
}

__global__ void s8_main(const float* __restrict__ obs, const float* __restrict__ ws,
                        float* __restrict__ out) {     // FLOAT32 output (reference returns f32)
    const int DRo[7] = {-1, -1, 0, 0, 0, -1, -1};
    const int DCo[7] = {0, 1, -1, 0, 1, -1, 0};
    __shared__ float sgl[121];
    __shared__ float nbs[121][7];
    __shared__ float att[121];
    __shared__ float bbar[2][25];
    __shared__ float g[51];
    __shared__ float cvec[19];
    __shared__ float tmp[2];
    int bid = blockIdx.x;
    int b = bid >> 1, pol = bid & 1;
    int t = threadIdx.x;
    if (t < 121) sgl[t] = obs[(b * 121 + t) * 2] - obs[(b * 121 + t) * 2 + 1];
    __syncthreads();
    float dots[2];
    if (t < 121) {
        int i = t / 11, j = t % 11;
        float nb[7];
        for (int k = 0; k < 7; k++) {
            int ii = i + DRo[k], jj = j + DCo[k];
            float v = (ii >= 0 && ii < 11 && jj >= 0 && jj < 11) ? sgl[ii * 11 + jj] : 0.f;
            nb[k] = v; nbs[t][k] = v;
        }
        for (int h = 0; h < 2; h++) {
            float acc = ws[O_PC + h * 121 + t];
            for (int k = 0; k < 7; k++) acc += ws[O_W + h * 25 + k] * nb[k];
            dots[h] = acc * INV_SQRT_D;
        }
    } else { dots[0] = dots[1] = -INFINITY; }
    for (int h = 0; h < 2; h++) {
        float m = blk_max2(dots[h], tmp);
        float e = (t < 121) ? expf(dots[h] - m) : 0.f;
        float s = blk_sum2(e, tmp);
        if (t < 121) att[t] = e / s;
        __syncthreads();
        if (t < 25) {
            float acc = 0.f;
            if (t < 7) { for (int p = 0; p < 121; p++) acc += att[p] * nbs[p][t]; }
            else { int j = t - 7; for (int p = 0; p < 121; p++) acc += att[p] * ws[O_POS + p * 18 + j]; }
            bbar[h][t] = acc;
        }
        __syncthreads();
    }
    if (t == 0) g[0] = 1.f;
    if (t < 50) g[1 + t] = bbar[t / 25][t % 25];
    __syncthreads();
    if (t < 19) {
        const float* Pr = ws + O_P + (pol * 19 + t) * 51;
        float a = 0.f;
        for (int c = 0; c < 51; c++) a += Pr[c] * g[c];
        cvec[t] = a;
    }
    __syncthreads();
    float d;
    if (t < 121) {
        d = cvec[0];
        for (int j = 0; j < 18; j++) d += ws[O_POS + t * 18 + j] * cvec[1 + j];
        d *= INV_SQRT_D;
    } else d = -INFINITY;
    float m = blk_max2(d, tmp);
    float e = (t < 121) ? expf(d - m) : 0.f;
    float s = blk_sum2(e, tmp);
    float ls = logf(s);
    if (t < 121) out[pol * 61952 + b * 121 + t] = d - m - ls;   // f32 store
}

extern "C" void kernel_launch(void* const* d_in, const int* in_sizes, int n_in,
                              void* d_out, int out_size, void* d_ws, size_t ws_size,
                              hipStream_t stream) {
    const float* obs     = (const float*)d_in[0];
    const float* b_first = (const float*)d_in[2];
    const float* W_kvx   = (const float*)d_in[3];
    const float* b_kvx   = (const float*)d_in[4];
    const float* W_kvb   = (const float*)d_in[5];
    const float* b_kvb   = (const float*)d_in[6];
    const float* W_q     = (const float*)d_in[7];
    const float* b_q     = (const float*)d_in[8];
    const float* W_fin   = (const float*)d_in[9];
    const float* b_fin   = (const float*)d_in[10];
    const float* W_sec   = (const float*)d_in[11];
    const float* b_sec   = (const float*)d_in[12];
    const float* W0_kp   = (const float*)d_in[13];
    const float* b0_kp   = (const float*)d_in[14];
    const float* W0_q    = (const float*)d_in[17];
    const float* b0_q    = (const float*)d_in[18];
    const float* W1_kp   = (const float*)d_in[19];
    const float* b1_kp   = (const float*)d_in[20];
    const float* W1_q    = (const float*)d_in[23];
    const float* b1_q    = (const float*)d_in[24];
    float* ws = (float*)d_ws;
    float* out = (float*)d_out;

    hipLaunchKernelGGL(s1_pos_x, dim3(1),   dim3(256), 0, stream, b_first, ws);
    hipLaunchKernelGGL(s2_kvx_qv, dim3(768), dim3(256), 0, stream, W_kvx, b_kvx, W_q, b_q, ws);
    hipLaunchKernelGGL(s3_w_vc, dim3(17), dim3(256), 0, stream, W_kvb, b_kvb, ws);
    hipLaunchKernelGGL(s4, dim3(257), dim3(256), 0, stream, W_fin, b_fin, W_kvb, ws);
    hipLaunchKernelGGL(s5, dim3(256), dim3(256), 0, stream, W_sec, b_sec, ws);
    hipLaunchKernelGGL(s6, dim3(512), dim3(256), 0, stream, W0_q, b0_q, W1_q, b1_q, ws);
    hipLaunchKernelGGL(s7_fold, dim3(485), dim3(256), 0, stream, W0_kp, b0_kp, W1_kp, b1_kp, ws);
    hipLaunchKernelGGL(s8_main, dim3(1024), dim3(128), 0, stream, obs, ws, out);
}